// Round 1
// baseline (5815.660 us; speedup 1.0000x reference)
//
#include <hip/hip_runtime.h>

#define HF 128  // feature width (F == H == 128)

// ---------- degree / dinv ----------
__global__ void deg_count(const int* __restrict__ col, float* __restrict__ deg, int E) {
    int e = blockIdx.x * blockDim.x + threadIdx.x;
    if (e < E) atomicAdd(&deg[col[e]], 1.0f);
}

__global__ void dinv_fin(float* __restrict__ deg, int N) {
    int i = blockIdx.x * blockDim.x + threadIdx.x;
    if (i < N) deg[i] = rsqrtf(deg[i] + 1.0f);
}

// ---------- GEMM: Y[N,128] = X[N,128] @ W[128,128] ----------
// 128 threads (one per output feature), 16 rows per block. X rows staged in LDS,
// W read from global (64KB, L2-resident, coalesced).
__global__ __launch_bounds__(128) void gemm128(const float* __restrict__ X,
                                               const float* __restrict__ W,
                                               float* __restrict__ Y, int N) {
    __shared__ float xs[16][HF];
    int t = threadIdx.x;
    int row0 = blockIdx.x * 16;
    for (int r = 0; r < 16; ++r) {
        int rr = row0 + r;
        xs[r][t] = (rr < N) ? X[(size_t)rr * HF + t] : 0.0f;
    }
    __syncthreads();
    for (int r0 = 0; r0 < 16; r0 += 4) {
        float a0 = 0.f, a1 = 0.f, a2 = 0.f, a3 = 0.f;
        #pragma unroll 8
        for (int f = 0; f < HF; ++f) {
            float w = W[f * HF + t];
            a0 += xs[r0 + 0][f] * w;
            a1 += xs[r0 + 1][f] * w;
            a2 += xs[r0 + 2][f] * w;
            a3 += xs[r0 + 3][f] * w;
        }
        int rr = row0 + r0;
        if (rr + 0 < N) Y[(size_t)(rr + 0) * HF + t] = a0;
        if (rr + 1 < N) Y[(size_t)(rr + 1) * HF + t] = a1;
        if (rr + 2 < N) Y[(size_t)(rr + 2) * HF + t] = a2;
        if (rr + 3 < N) Y[(size_t)(rr + 3) * HF + t] = a3;
    }
}

// ---------- edge scatter: AGG[col] += dinv[row]*dinv[col] * XW[row] ----------
// 32 lanes per edge, 4 features per lane (float4 gather), 8 edges per 256-thread block.
__global__ void scatter_edges(const int* __restrict__ row, const int* __restrict__ col,
                              const float* __restrict__ dinv, const float* __restrict__ XW,
                              float* __restrict__ AGG, int E) {
    int e = blockIdx.x * 8 + (threadIdx.x >> 5);
    int j = threadIdx.x & 31;
    if (e >= E) return;
    int r = row[e], c = col[e];
    float coef = dinv[r] * dinv[c];
    const float4 v = *reinterpret_cast<const float4*>(XW + (size_t)r * HF + j * 4);
    float* dst = AGG + (size_t)c * HF + j * 4;
    atomicAdd(dst + 0, coef * v.x);
    atomicAdd(dst + 1, coef * v.y);
    atomicAdd(dst + 2, coef * v.z);
    atomicAdd(dst + 3, coef * v.w);
}

// ---------- self-loop + bias: AGG += dinv^2 * XW + b ----------
__global__ void selfloop_bias(const float* __restrict__ dinv, const float* __restrict__ XW,
                              const float* __restrict__ b, float* __restrict__ AGG, int total) {
    int idx = blockIdx.x * blockDim.x + threadIdx.x;
    if (idx >= total) return;
    int n = idx >> 7, h = idx & (HF - 1);
    float di = dinv[n];
    AGG[idx] += di * di * XW[idx] + b[h];
}

// ---------- BN stats (per-feature sum & sumsq over nodes) ----------
__global__ __launch_bounds__(128) void bn_stats(const float* __restrict__ Y,
                                                float* __restrict__ ssum,
                                                float* __restrict__ ssq, int N) {
    int t = threadIdx.x;
    float s = 0.f, sq = 0.f;
    for (int n = blockIdx.x; n < N; n += gridDim.x) {
        float v = Y[(size_t)n * HF + t];
        s += v;
        sq += v * v;
    }
    atomicAdd(&ssum[t], s);
    atomicAdd(&ssq[t], sq);
}

__global__ __launch_bounds__(128) void bn_finalize(const float* __restrict__ ssum,
                                                   const float* __restrict__ ssq,
                                                   const float* __restrict__ gamma,
                                                   const float* __restrict__ beta,
                                                   float* __restrict__ scale,
                                                   float* __restrict__ shift, int N) {
    int t = threadIdx.x;
    float invn = 1.0f / (float)N;
    float mu = ssum[t] * invn;
    float var = ssq[t] * invn - mu * mu;
    float sc = gamma[t] * rsqrtf(var + 1e-5f);
    scale[t] = sc;
    shift[t] = beta[t] - mu * sc;
}

__global__ void bn_relu(float* __restrict__ Y, const float* __restrict__ scale,
                        const float* __restrict__ shift, int total) {
    int idx = blockIdx.x * blockDim.x + threadIdx.x;
    if (idx >= total) return;
    int h = idx & (HF - 1);
    float v = Y[idx] * scale[h] + shift[h];
    Y[idx] = fmaxf(v, 0.0f);
}

// ---------- pooling ----------
__global__ void pool_cnt(const int* __restrict__ batch, float* __restrict__ cnt, int N) {
    int n = blockIdx.x * blockDim.x + threadIdx.x;
    if (n < N) atomicAdd(&cnt[batch[n]], 1.0f);
}

__global__ void pool_feats(const float* __restrict__ Y, const int* __restrict__ batch,
                           float* __restrict__ hsum, unsigned int* __restrict__ hmax, int total) {
    int idx = blockIdx.x * blockDim.x + threadIdx.x;
    if (idx >= total) return;
    int n = idx >> 7, h = idx & (HF - 1);
    int g = batch[n];
    float v = Y[idx];
    atomicAdd(&hsum[g * HF + h], v);
    atomicMax(&hmax[g * HF + h], __float_as_uint(v));  // v >= 0 post-ReLU
}

// ---------- classifier: out[g, :3] = [mean | max | sum] @ Wc + bc ----------
__global__ __launch_bounds__(128) void classifier(const float* __restrict__ hsum,
                                                  const unsigned int* __restrict__ hmax,
                                                  const float* __restrict__ cnt,
                                                  const float* __restrict__ Wc,
                                                  const float* __restrict__ bc,
                                                  float* __restrict__ out) {
    int g = blockIdx.x;
    int t = threadIdx.x;
    float c = cnt[g];
    float s = hsum[g * HF + t];
    float mean = s / fmaxf(c, 1.0f);
    float mx = __uint_as_float(hmax[g * HF + t]);  // 0 for empty graphs (memset) == guard
    float p0 = mean * Wc[t * 3 + 0] + mx * Wc[(HF + t) * 3 + 0] + s * Wc[(2 * HF + t) * 3 + 0];
    float p1 = mean * Wc[t * 3 + 1] + mx * Wc[(HF + t) * 3 + 1] + s * Wc[(2 * HF + t) * 3 + 1];
    float p2 = mean * Wc[t * 3 + 2] + mx * Wc[(HF + t) * 3 + 2] + s * Wc[(2 * HF + t) * 3 + 2];
    __shared__ float red[3][HF];
    red[0][t] = p0; red[1][t] = p1; red[2][t] = p2;
    __syncthreads();
    for (int off = 64; off > 0; off >>= 1) {
        if (t < off) {
            red[0][t] += red[0][t + off];
            red[1][t] += red[1][t + off];
            red[2][t] += red[2][t + off];
        }
        __syncthreads();
    }
    if (t < 3) out[g * 3 + t] = red[t][0] + bc[t];
}

extern "C" void kernel_launch(void* const* d_in, const int* in_sizes, int n_in,
                              void* d_out, int out_size, void* d_ws, size_t ws_size,
                              hipStream_t stream) {
    const float* x    = (const float*)d_in[0];
    const int*   ei   = (const int*)d_in[1];
    const int*   batch= (const int*)d_in[2];
    const float* W1   = (const float*)d_in[3];
    const float* b1   = (const float*)d_in[4];
    const float* g1   = (const float*)d_in[5];
    const float* be1  = (const float*)d_in[6];
    const float* W2   = (const float*)d_in[7];
    const float* b2   = (const float*)d_in[8];
    const float* g2   = (const float*)d_in[9];
    const float* be2  = (const float*)d_in[10];
    const float* Wc   = (const float*)d_in[11];
    const float* bc   = (const float*)d_in[12];
    float* out = (float*)d_out;

    const int N = in_sizes[0] / HF;
    const int E = in_sizes[1] / 2;
    const int NG = 256;
    const int* row = ei;
    const int* col = ei + E;
    const int total = N * HF;

    // workspace carve-up (256B aligned)
    char* w = (char*)d_ws;
    size_t off = 0;
    auto alloc = [&](size_t bytes) -> void* {
        void* p = w + off;
        off += (bytes + 255) & ~(size_t)255;
        return p;
    };
    float*        dinv  = (float*)alloc((size_t)N * 4);
    float*        ssum  = (float*)alloc(HF * 4);
    float*        ssq   = (float*)alloc(HF * 4);
    float*        scale = (float*)alloc(HF * 4);
    float*        shift = (float*)alloc(HF * 4);
    float*        cnt   = (float*)alloc(NG * 4);
    float*        hsum  = (float*)alloc((size_t)NG * HF * 4);
    unsigned int* hmax  = (unsigned int*)alloc((size_t)NG * HF * 4);
    float*        A     = (float*)alloc((size_t)total * 4);  // xw / hw
    float*        B     = (float*)alloc((size_t)total * 4);  // agg / h

    const int T256 = 256;
    int gridE   = (E + T256 - 1) / T256;
    int gridN   = (N + T256 - 1) / T256;
    int gridNH  = (total + T256 - 1) / T256;
    int gridSc  = (E + 7) / 8;
    int gridGemm = (N + 15) / 16;

    // --- degrees ---
    hipMemsetAsync(dinv, 0, (size_t)N * 4, stream);
    deg_count<<<gridE, T256, 0, stream>>>(col, dinv, E);
    dinv_fin<<<gridN, T256, 0, stream>>>(dinv, N);

    // --- conv1 ---
    gemm128<<<gridGemm, 128, 0, stream>>>(x, W1, A, N);
    hipMemsetAsync(B, 0, (size_t)total * 4, stream);
    scatter_edges<<<gridSc, T256, 0, stream>>>(row, col, dinv, A, B, E);
    selfloop_bias<<<gridNH, T256, 0, stream>>>(dinv, A, b1, B, total);
    hipMemsetAsync(ssum, 0, 2 * ((HF * 4 + 255) & ~255), stream);  // ssum+ssq contiguous
    bn_stats<<<512, 128, 0, stream>>>(B, ssum, ssq, N);
    bn_finalize<<<1, 128, 0, stream>>>(ssum, ssq, g1, be1, scale, shift, N);
    bn_relu<<<gridNH, T256, 0, stream>>>(B, scale, shift, total);

    // --- conv2 ---
    gemm128<<<gridGemm, 128, 0, stream>>>(B, W2, A, N);
    hipMemsetAsync(B, 0, (size_t)total * 4, stream);
    scatter_edges<<<gridSc, T256, 0, stream>>>(row, col, dinv, A, B, E);
    selfloop_bias<<<gridNH, T256, 0, stream>>>(dinv, A, b2, B, total);
    hipMemsetAsync(ssum, 0, 2 * ((HF * 4 + 255) & ~255), stream);
    bn_stats<<<512, 128, 0, stream>>>(B, ssum, ssq, N);
    bn_finalize<<<1, 128, 0, stream>>>(ssum, ssq, g2, be2, scale, shift, N);
    bn_relu<<<gridNH, T256, 0, stream>>>(B, scale, shift, total);

    // --- pooling ---
    // cnt + hsum + hmax are contiguous in ws: zero in one shot
    size_t poolBytes = ((size_t)NG * 4 + 255 & ~(size_t)255)
                     + (((size_t)NG * HF * 4 + 255) & ~(size_t)255) * 2;
    hipMemsetAsync(cnt, 0, poolBytes, stream);
    pool_cnt<<<gridN, T256, 0, stream>>>(batch, cnt, N);
    pool_feats<<<gridNH, T256, 0, stream>>>(B, batch, hsum, hmax, total);

    // --- classifier ---
    classifier<<<NG, 128, 0, stream>>>(hsum, hmax, cnt, Wc, bc, out);
}

// Round 2
// 777.903 us; speedup vs baseline: 7.4761x; 7.4761x over previous
//
#include <hip/hip_runtime.h>

#define HF 128  // feature width (F == H == 128)

// ---------- degree histogram (int) ----------
__global__ void deg_count(const int* __restrict__ col, int* __restrict__ cnt, int E) {
    int e = blockIdx.x * blockDim.x + threadIdx.x;
    if (e < E) atomicAdd(&cnt[col[e]], 1);
}

__global__ void dinv_fin(const int* __restrict__ cnt, float* __restrict__ dinv, int N) {
    int i = blockIdx.x * blockDim.x + threadIdx.x;
    if (i < N) dinv[i] = rsqrtf((float)cnt[i] + 1.0f);
}

// ---------- 3-pass exclusive scan over cnt -> rowptr (N <= 65536) ----------
__global__ __launch_bounds__(256) void scan_pass1(const int* __restrict__ cnt,
                                                  int* __restrict__ rowptr,
                                                  int* __restrict__ blocksum, int N) {
    __shared__ int s[256];
    int t = threadIdx.x;
    int i = blockIdx.x * 256 + t;
    int v = (i < N) ? cnt[i] : 0;
    s[t] = v;
    __syncthreads();
    for (int o = 1; o < 256; o <<= 1) {
        int tv = (t >= o) ? s[t - o] : 0;
        __syncthreads();
        s[t] += tv;
        __syncthreads();
    }
    if (i < N) rowptr[i] = s[t] - v;  // block-local exclusive
    if (t == 255) blocksum[blockIdx.x] = s[255];
}

__global__ __launch_bounds__(256) void scan_pass2(int* __restrict__ blocksum, int nb,
                                                  int* __restrict__ rowptr, int N, int E) {
    __shared__ int s[256];
    int t = threadIdx.x;
    int v = (t < nb) ? blocksum[t] : 0;
    s[t] = v;
    __syncthreads();
    for (int o = 1; o < 256; o <<= 1) {
        int tv = (t >= o) ? s[t - o] : 0;
        __syncthreads();
        s[t] += tv;
        __syncthreads();
    }
    if (t < nb) blocksum[t] = s[t] - v;  // exclusive block bases
    if (t == 0) rowptr[N] = E;
}

__global__ __launch_bounds__(256) void scan_pass3(int* __restrict__ rowptr,
                                                  const int* __restrict__ blocksum, int N) {
    int i = blockIdx.x * 256 + threadIdx.x;
    if (i < N) rowptr[i] += blocksum[blockIdx.x];
}

// ---------- CSR fill: bucket edges by col ----------
__global__ void csr_fill(const int* __restrict__ row, const int* __restrict__ col,
                         const float* __restrict__ dinv, const int* __restrict__ rowptr,
                         int* __restrict__ fill, int* __restrict__ srow,
                         float* __restrict__ sdr, int E) {
    int e = blockIdx.x * blockDim.x + threadIdx.x;
    if (e >= E) return;
    int r = row[e], c = col[e];
    int pos = rowptr[c] + atomicAdd(&fill[c], 1);
    srow[pos] = r;
    sdr[pos] = dinv[r];  // pre-gathered dinv[row]
}

// ---------- GEMM: Y[N,128] = X[N,128] @ W[128,128] ----------
__global__ __launch_bounds__(128) void gemm128(const float* __restrict__ X,
                                               const float* __restrict__ W,
                                               float* __restrict__ Y, int N) {
    __shared__ float xs[16][HF];
    int t = threadIdx.x;
    int row0 = blockIdx.x * 16;
    for (int r = 0; r < 16; ++r) {
        int rr = row0 + r;
        xs[r][t] = (rr < N) ? X[(size_t)rr * HF + t] : 0.0f;
    }
    __syncthreads();
    for (int r0 = 0; r0 < 16; r0 += 4) {
        float a0 = 0.f, a1 = 0.f, a2 = 0.f, a3 = 0.f;
        #pragma unroll 8
        for (int f = 0; f < HF; ++f) {
            float w = W[f * HF + t];
            a0 += xs[r0 + 0][f] * w;
            a1 += xs[r0 + 1][f] * w;
            a2 += xs[r0 + 2][f] * w;
            a3 += xs[r0 + 3][f] * w;
        }
        int rr = row0 + r0;
        if (rr + 0 < N) Y[(size_t)(rr + 0) * HF + t] = a0;
        if (rr + 1 < N) Y[(size_t)(rr + 1) * HF + t] = a1;
        if (rr + 2 < N) Y[(size_t)(rr + 2) * HF + t] = a2;
        if (rr + 3 < N) Y[(size_t)(rr + 3) * HF + t] = a3;
    }
}

// ---------- gather-side conv: OUT[c] = dinv[c]*(sum_r dinv[r]*XW[r] + dinv[c]*XW[c]) + b ----------
// 32 lanes per node, 4 features/lane (float4). 8 nodes per 256-thread block.
__global__ __launch_bounds__(256) void gather_conv(const int* __restrict__ rowptr,
                                                   const int* __restrict__ srow,
                                                   const float* __restrict__ sdr,
                                                   const float* __restrict__ dinv,
                                                   const float* __restrict__ XW,
                                                   const float* __restrict__ b,
                                                   float* __restrict__ OUT, int N) {
    int c = blockIdx.x * 8 + (threadIdx.x >> 5);
    int j = threadIdx.x & 31;
    if (c >= N) return;
    int e = rowptr[c], end = rowptr[c + 1];
    float4 acc = {0.f, 0.f, 0.f, 0.f};
    // 2-deep manual pipeline for MLP
    for (; e + 1 < end; e += 2) {
        int r0 = srow[e], r1 = srow[e + 1];
        float d0 = sdr[e], d1 = sdr[e + 1];
        float4 v0 = *reinterpret_cast<const float4*>(XW + (size_t)r0 * HF + j * 4);
        float4 v1 = *reinterpret_cast<const float4*>(XW + (size_t)r1 * HF + j * 4);
        acc.x += d0 * v0.x + d1 * v1.x;
        acc.y += d0 * v0.y + d1 * v1.y;
        acc.z += d0 * v0.z + d1 * v1.z;
        acc.w += d0 * v0.w + d1 * v1.w;
    }
    if (e < end) {
        int r0 = srow[e];
        float d0 = sdr[e];
        float4 v0 = *reinterpret_cast<const float4*>(XW + (size_t)r0 * HF + j * 4);
        acc.x += d0 * v0.x;
        acc.y += d0 * v0.y;
        acc.z += d0 * v0.z;
        acc.w += d0 * v0.w;
    }
    float dc = dinv[c];
    float4 xv = *reinterpret_cast<const float4*>(XW + (size_t)c * HF + j * 4);
    float4 bb = *reinterpret_cast<const float4*>(b + j * 4);
    float4 o;
    o.x = dc * (acc.x + dc * xv.x) + bb.x;
    o.y = dc * (acc.y + dc * xv.y) + bb.y;
    o.z = dc * (acc.z + dc * xv.z) + bb.z;
    o.w = dc * (acc.w + dc * xv.w) + bb.w;
    *reinterpret_cast<float4*>(OUT + (size_t)c * HF + j * 4) = o;
}

// ---------- BN stats ----------
__global__ __launch_bounds__(128) void bn_stats(const float* __restrict__ Y,
                                                float* __restrict__ ssum,
                                                float* __restrict__ ssq, int N) {
    int t = threadIdx.x;
    float s = 0.f, sq = 0.f;
    for (int n = blockIdx.x; n < N; n += gridDim.x) {
        float v = Y[(size_t)n * HF + t];
        s += v;
        sq += v * v;
    }
    atomicAdd(&ssum[t], s);
    atomicAdd(&ssq[t], sq);
}

__global__ __launch_bounds__(128) void bn_finalize(const float* __restrict__ ssum,
                                                   const float* __restrict__ ssq,
                                                   const float* __restrict__ gamma,
                                                   const float* __restrict__ beta,
                                                   float* __restrict__ scale,
                                                   float* __restrict__ shift, int N) {
    int t = threadIdx.x;
    float invn = 1.0f / (float)N;
    float mu = ssum[t] * invn;
    float var = ssq[t] * invn - mu * mu;
    float sc = gamma[t] * rsqrtf(var + 1e-5f);
    scale[t] = sc;
    shift[t] = beta[t] - mu * sc;
}

__global__ void bn_relu(float* __restrict__ Y, const float* __restrict__ scale,
                        const float* __restrict__ shift, int total) {
    int idx = blockIdx.x * blockDim.x + threadIdx.x;
    if (idx >= total) return;
    int h = idx & (HF - 1);
    float v = Y[idx] * scale[h] + shift[h];
    Y[idx] = fmaxf(v, 0.0f);
}

// ---------- pooling ----------
__global__ void pool_cnt(const int* __restrict__ batch, float* __restrict__ cnt, int N) {
    int n = blockIdx.x * blockDim.x + threadIdx.x;
    if (n < N) atomicAdd(&cnt[batch[n]], 1.0f);
}

__global__ void pool_feats(const float* __restrict__ Y, const int* __restrict__ batch,
                           float* __restrict__ hsum, unsigned int* __restrict__ hmax, int total) {
    int idx = blockIdx.x * blockDim.x + threadIdx.x;
    if (idx >= total) return;
    int n = idx >> 7, h = idx & (HF - 1);
    int g = batch[n];
    float v = Y[idx];
    atomicAdd(&hsum[g * HF + h], v);
    atomicMax(&hmax[g * HF + h], __float_as_uint(v));  // v >= 0 post-ReLU
}

// ---------- classifier ----------
__global__ __launch_bounds__(128) void classifier(const float* __restrict__ hsum,
                                                  const unsigned int* __restrict__ hmax,
                                                  const float* __restrict__ cnt,
                                                  const float* __restrict__ Wc,
                                                  const float* __restrict__ bc,
                                                  float* __restrict__ out) {
    int g = blockIdx.x;
    int t = threadIdx.x;
    float c = cnt[g];
    float s = hsum[g * HF + t];
    float mean = s / fmaxf(c, 1.0f);
    float mx = __uint_as_float(hmax[g * HF + t]);  // 0 for empty graphs == guard
    float p0 = mean * Wc[t * 3 + 0] + mx * Wc[(HF + t) * 3 + 0] + s * Wc[(2 * HF + t) * 3 + 0];
    float p1 = mean * Wc[t * 3 + 1] + mx * Wc[(HF + t) * 3 + 1] + s * Wc[(2 * HF + t) * 3 + 1];
    float p2 = mean * Wc[t * 3 + 2] + mx * Wc[(HF + t) * 3 + 2] + s * Wc[(2 * HF + t) * 3 + 2];
    __shared__ float red[3][HF];
    red[0][t] = p0; red[1][t] = p1; red[2][t] = p2;
    __syncthreads();
    for (int off = 64; off > 0; off >>= 1) {
        if (t < off) {
            red[0][t] += red[0][t + off];
            red[1][t] += red[1][t + off];
            red[2][t] += red[2][t + off];
        }
        __syncthreads();
    }
    if (t < 3) out[g * 3 + t] = red[t][0] + bc[t];
}

extern "C" void kernel_launch(void* const* d_in, const int* in_sizes, int n_in,
                              void* d_out, int out_size, void* d_ws, size_t ws_size,
                              hipStream_t stream) {
    const float* x    = (const float*)d_in[0];
    const int*   ei   = (const int*)d_in[1];
    const int*   batch= (const int*)d_in[2];
    const float* W1   = (const float*)d_in[3];
    const float* b1   = (const float*)d_in[4];
    const float* g1   = (const float*)d_in[5];
    const float* be1  = (const float*)d_in[6];
    const float* W2   = (const float*)d_in[7];
    const float* b2   = (const float*)d_in[8];
    const float* g2   = (const float*)d_in[9];
    const float* be2  = (const float*)d_in[10];
    const float* Wc   = (const float*)d_in[11];
    const float* bc   = (const float*)d_in[12];
    float* out = (float*)d_out;

    const int N = in_sizes[0] / HF;
    const int E = in_sizes[1] / 2;
    const int NG = 256;
    const int* row = ei;
    const int* col = ei + E;
    const int total = N * HF;

    // workspace carve-up (256B aligned)
    char* w = (char*)d_ws;
    size_t off = 0;
    auto alloc = [&](size_t bytes) -> void* {
        void* p = w + off;
        off += (bytes + 255) & ~(size_t)255;
        return p;
    };
    int*          cnt_in   = (int*)alloc((size_t)N * 4);        // \ zeroed together
    int*          fill     = (int*)alloc((size_t)N * 4);        // /
    float*        dinv     = (float*)alloc((size_t)N * 4);
    int*          rowptr   = (int*)alloc(((size_t)N + 1) * 4);
    int*          blocksum = (int*)alloc(256 * 4);
    int*          srow     = (int*)alloc((size_t)E * 4);
    float*        sdr      = (float*)alloc((size_t)E * 4);
    float*        ssum     = (float*)alloc(HF * 4);             // \ zeroed together
    float*        ssq      = (float*)alloc(HF * 4);             // /
    float*        scale    = (float*)alloc(HF * 4);
    float*        shift    = (float*)alloc(HF * 4);
    float*        cnt      = (float*)alloc(NG * 4);             // \ pool bufs zeroed together
    float*        hsum     = (float*)alloc((size_t)NG * HF * 4);// |
    unsigned int* hmax     = (unsigned int*)alloc((size_t)NG * HF * 4); // /
    float*        A        = (float*)alloc((size_t)total * 4);  // xw / hw
    float*        B        = (float*)alloc((size_t)total * 4);  // agg / h

    const int T256 = 256;
    int gridE    = (E + T256 - 1) / T256;
    int gridN    = (N + T256 - 1) / T256;
    int gridNH   = (total + T256 - 1) / T256;
    int gridGa   = (N + 7) / 8;
    int gridGemm = (N + 15) / 16;
    int nb       = (N + 255) / 256;  // scan blocks (requires N <= 65536)

    // --- CSR build (once; reused by both convs) ---
    hipMemsetAsync(cnt_in, 0, 2 * (((size_t)N * 4 + 255) & ~(size_t)255), stream);  // cnt_in+fill
    deg_count<<<gridE, T256, 0, stream>>>(col, cnt_in, E);
    dinv_fin<<<gridN, T256, 0, stream>>>(cnt_in, dinv, N);
    scan_pass1<<<nb, 256, 0, stream>>>(cnt_in, rowptr, blocksum, N);
    scan_pass2<<<1, 256, 0, stream>>>(blocksum, nb, rowptr, N, E);
    scan_pass3<<<nb, 256, 0, stream>>>(rowptr, blocksum, N);
    csr_fill<<<gridE, T256, 0, stream>>>(row, col, dinv, rowptr, fill, srow, sdr, E);

    // --- conv1 ---
    gemm128<<<gridGemm, 128, 0, stream>>>(x, W1, A, N);
    gather_conv<<<gridGa, T256, 0, stream>>>(rowptr, srow, sdr, dinv, A, b1, B, N);
    hipMemsetAsync(ssum, 0, 2 * ((HF * 4 + 255) & ~255), stream);
    bn_stats<<<512, 128, 0, stream>>>(B, ssum, ssq, N);
    bn_finalize<<<1, 128, 0, stream>>>(ssum, ssq, g1, be1, scale, shift, N);
    bn_relu<<<gridNH, T256, 0, stream>>>(B, scale, shift, total);

    // --- conv2 ---
    gemm128<<<gridGemm, 128, 0, stream>>>(B, W2, A, N);
    gather_conv<<<gridGa, T256, 0, stream>>>(rowptr, srow, sdr, dinv, A, b2, B, N);
    hipMemsetAsync(ssum, 0, 2 * ((HF * 4 + 255) & ~255), stream);
    bn_stats<<<512, 128, 0, stream>>>(B, ssum, ssq, N);
    bn_finalize<<<1, 128, 0, stream>>>(ssum, ssq, g2, be2, scale, shift, N);
    bn_relu<<<gridNH, T256, 0, stream>>>(B, scale, shift, total);

    // --- pooling ---
    size_t poolBytes = (((size_t)NG * 4 + 255) & ~(size_t)255)
                     + (((size_t)NG * HF * 4 + 255) & ~(size_t)255) * 2;
    hipMemsetAsync(cnt, 0, poolBytes, stream);
    pool_cnt<<<gridN, T256, 0, stream>>>(batch, cnt, N);
    pool_feats<<<gridNH, T256, 0, stream>>>(B, batch, hsum, hmax, total);

    // --- classifier ---
    classifier<<<NG, 128, 0, stream>>>(hsum, hmax, cnt, Wc, bc, out);
}

// Round 3
// 535.625 us; speedup vs baseline: 10.8577x; 1.4523x over previous
//
#include <hip/hip_runtime.h>

#define HF 128  // feature width (F == H == 128)

__device__ __forceinline__ float bf2f(unsigned short u) {
    return __uint_as_float(((unsigned)u) << 16);
}
__device__ __forceinline__ unsigned short f2bf(float f) {
    unsigned u = __float_as_uint(f);
    unsigned rounding = 0x7FFF + ((u >> 16) & 1);  // round-to-nearest-even
    return (unsigned short)((u + rounding) >> 16);
}

// ---------- degree histogram (int) ----------
__global__ void deg_count(const int* __restrict__ col, int* __restrict__ cnt, int E) {
    int e = blockIdx.x * blockDim.x + threadIdx.x;
    if (e < E) atomicAdd(&cnt[col[e]], 1);
}

__global__ void dinv_fin(const int* __restrict__ cnt, float* __restrict__ dinv, int N) {
    int i = blockIdx.x * blockDim.x + threadIdx.x;
    if (i < N) dinv[i] = rsqrtf((float)cnt[i] + 1.0f);
}

// ---------- 3-pass exclusive scan over cnt -> rowptr (N <= 65536) ----------
__global__ __launch_bounds__(256) void scan_pass1(const int* __restrict__ cnt,
                                                  int* __restrict__ rowptr,
                                                  int* __restrict__ blocksum, int N) {
    __shared__ int s[256];
    int t = threadIdx.x;
    int i = blockIdx.x * 256 + t;
    int v = (i < N) ? cnt[i] : 0;
    s[t] = v;
    __syncthreads();
    for (int o = 1; o < 256; o <<= 1) {
        int tv = (t >= o) ? s[t - o] : 0;
        __syncthreads();
        s[t] += tv;
        __syncthreads();
    }
    if (i < N) rowptr[i] = s[t] - v;  // block-local exclusive
    if (t == 255) blocksum[blockIdx.x] = s[255];
}

__global__ __launch_bounds__(256) void scan_pass2(int* __restrict__ blocksum, int nb,
                                                  int* __restrict__ rowptr, int N, int E) {
    __shared__ int s[256];
    int t = threadIdx.x;
    int v = (t < nb) ? blocksum[t] : 0;
    s[t] = v;
    __syncthreads();
    for (int o = 1; o < 256; o <<= 1) {
        int tv = (t >= o) ? s[t - o] : 0;
        __syncthreads();
        s[t] += tv;
        __syncthreads();
    }
    if (t < nb) blocksum[t] = s[t] - v;  // exclusive block bases
    if (t == 0) rowptr[N] = E;
}

// also seeds fill[] with the final rowptr so csr_fill can atomicAdd it directly
__global__ __launch_bounds__(256) void scan_pass3(int* __restrict__ rowptr,
                                                  const int* __restrict__ blocksum,
                                                  int* __restrict__ fill, int N) {
    int i = blockIdx.x * 256 + threadIdx.x;
    if (i < N) {
        int v = rowptr[i] + blocksum[blockIdx.x];
        rowptr[i] = v;
        fill[i] = v;
    }
}

// ---------- CSR fill: bucket edges by col, packed {row, dinv[row]} ----------
__global__ void csr_fill(const int* __restrict__ row, const int* __restrict__ col,
                         const float* __restrict__ dinv, int* __restrict__ fill,
                         int2* __restrict__ srs, int E) {
    int e = blockIdx.x * blockDim.x + threadIdx.x;
    if (e >= E) return;
    int r = row[e], c = col[e];
    int pos = atomicAdd(&fill[c], 1);
    srs[pos] = make_int2(r, __float_as_int(dinv[r]));
}

// ---------- GEMM: Y[N,128](bf16) = BNReLU?(X[N,128]) @ W[128,128] ----------
__global__ __launch_bounds__(128) void gemm128(const float* __restrict__ X,
                                               const float* __restrict__ W,
                                               unsigned short* __restrict__ Y,
                                               const float* __restrict__ scale,
                                               const float* __restrict__ shift,
                                               int N, int applyBN) {
    __shared__ float xs[16][HF];
    int t = threadIdx.x;
    int row0 = blockIdx.x * 16;
    float sc = applyBN ? scale[t] : 1.0f;
    float sh = applyBN ? shift[t] : 0.0f;
    for (int r = 0; r < 16; ++r) {
        int rr = row0 + r;
        float v = (rr < N) ? X[(size_t)rr * HF + t] : 0.0f;
        if (applyBN) v = fmaxf(v * sc + sh, 0.0f);
        xs[r][t] = v;
    }
    __syncthreads();
    for (int r0 = 0; r0 < 16; r0 += 4) {
        float a0 = 0.f, a1 = 0.f, a2 = 0.f, a3 = 0.f;
        #pragma unroll 8
        for (int f = 0; f < HF; ++f) {
            float w = W[f * HF + t];
            a0 += xs[r0 + 0][f] * w;
            a1 += xs[r0 + 1][f] * w;
            a2 += xs[r0 + 2][f] * w;
            a3 += xs[r0 + 3][f] * w;
        }
        int rr = row0 + r0;
        if (rr + 0 < N) Y[(size_t)(rr + 0) * HF + t] = f2bf(a0);
        if (rr + 1 < N) Y[(size_t)(rr + 1) * HF + t] = f2bf(a1);
        if (rr + 2 < N) Y[(size_t)(rr + 2) * HF + t] = f2bf(a2);
        if (rr + 3 < N) Y[(size_t)(rr + 3) * HF + t] = f2bf(a3);
    }
}

// ---------- gather-side conv (bf16 XW): OUT[c] = dc*(sum_r d_r*XW[r] + dc*XW[c]) + b ----------
__global__ __launch_bounds__(256) void gather_conv(const int* __restrict__ rowptr,
                                                   const int2* __restrict__ srs,
                                                   const float* __restrict__ dinv,
                                                   const unsigned short* __restrict__ XW,
                                                   const float* __restrict__ b,
                                                   float* __restrict__ OUT, int N) {
    int c = blockIdx.x * 8 + (threadIdx.x >> 5);
    int j = threadIdx.x & 31;
    if (c >= N) return;
    int e = rowptr[c], end = rowptr[c + 1];
    float ax = 0.f, ay = 0.f, az = 0.f, aw = 0.f;
    for (; e + 1 < end; e += 2) {
        int2 p0 = srs[e], p1 = srs[e + 1];
        float d0 = __int_as_float(p0.y), d1 = __int_as_float(p1.y);
        ushort4 u0 = *reinterpret_cast<const ushort4*>(XW + (size_t)p0.x * HF + j * 4);
        ushort4 u1 = *reinterpret_cast<const ushort4*>(XW + (size_t)p1.x * HF + j * 4);
        ax += d0 * bf2f(u0.x) + d1 * bf2f(u1.x);
        ay += d0 * bf2f(u0.y) + d1 * bf2f(u1.y);
        az += d0 * bf2f(u0.z) + d1 * bf2f(u1.z);
        aw += d0 * bf2f(u0.w) + d1 * bf2f(u1.w);
    }
    if (e < end) {
        int2 p0 = srs[e];
        float d0 = __int_as_float(p0.y);
        ushort4 u0 = *reinterpret_cast<const ushort4*>(XW + (size_t)p0.x * HF + j * 4);
        ax += d0 * bf2f(u0.x);
        ay += d0 * bf2f(u0.y);
        az += d0 * bf2f(u0.z);
        aw += d0 * bf2f(u0.w);
    }
    float dc = dinv[c];
    ushort4 xv = *reinterpret_cast<const ushort4*>(XW + (size_t)c * HF + j * 4);
    float4 bb = *reinterpret_cast<const float4*>(b + j * 4);
    float4 o;
    o.x = dc * (ax + dc * bf2f(xv.x)) + bb.x;
    o.y = dc * (ay + dc * bf2f(xv.y)) + bb.y;
    o.z = dc * (az + dc * bf2f(xv.z)) + bb.z;
    o.w = dc * (aw + dc * bf2f(xv.w)) + bb.w;
    *reinterpret_cast<float4*>(OUT + (size_t)c * HF + j * 4) = o;
}

// ---------- BN stats ----------
__global__ __launch_bounds__(128) void bn_stats(const float* __restrict__ Y,
                                                float* __restrict__ ssum,
                                                float* __restrict__ ssq, int N) {
    int t = threadIdx.x;
    float s = 0.f, sq = 0.f;
    for (int n = blockIdx.x; n < N; n += gridDim.x) {
        float v = Y[(size_t)n * HF + t];
        s += v;
        sq += v * v;
    }
    atomicAdd(&ssum[t], s);
    atomicAdd(&ssq[t], sq);
}

__global__ __launch_bounds__(128) void bn_finalize(const float* __restrict__ ssum,
                                                   const float* __restrict__ ssq,
                                                   const float* __restrict__ gamma,
                                                   const float* __restrict__ beta,
                                                   float* __restrict__ scale,
                                                   float* __restrict__ shift, int N) {
    int t = threadIdx.x;
    float invn = 1.0f / (float)N;
    float mu = ssum[t] * invn;
    float var = ssq[t] * invn - mu * mu;
    float sc = gamma[t] * rsqrtf(var + 1e-5f);
    scale[t] = sc;
    shift[t] = beta[t] - mu * sc;
}

// ---------- graph boundaries (batch is sorted): gstart[g] = lower_bound(batch, g) ----------
__global__ void graph_bounds(const int* __restrict__ batch, int* __restrict__ gstart,
                             int N, int NG) {
    int g = blockIdx.x * blockDim.x + threadIdx.x;
    if (g > NG) return;
    int lo = 0, hi = N;
    while (lo < hi) {
        int mid = (lo + hi) >> 1;
        if (batch[mid] < g) lo = mid + 1; else hi = mid;
    }
    gstart[g] = lo;
}

// ---------- fused BN2+ReLU + mean/max/sum pool + classifier ----------
// one block per graph; 256 threads = 128 features x 2 row-halves.
__global__ __launch_bounds__(256) void pool_classify(const float* __restrict__ B,
                                                     const int* __restrict__ gstart,
                                                     const float* __restrict__ scale,
                                                     const float* __restrict__ shift,
                                                     const float* __restrict__ Wc,
                                                     const float* __restrict__ bc,
                                                     float* __restrict__ out) {
    int g = blockIdx.x;
    int t = threadIdx.x & 127;
    int half = threadIdx.x >> 7;
    int s0 = gstart[g], s1 = gstart[g + 1];
    float sc = scale[t], sh = shift[t];
    float sum = 0.f, mx = 0.f;  // 0-init == empty-graph guard (post-ReLU v >= 0)
    for (int n = s0 + half; n < s1; n += 2) {
        float v = fmaxf(B[(size_t)n * HF + t] * sc + sh, 0.0f);
        sum += v;
        mx = fmaxf(mx, v);
    }
    __shared__ float shsum[2][HF], shmax[2][HF];
    __shared__ float red[3][HF];
    shsum[half][t] = sum;
    shmax[half][t] = mx;
    __syncthreads();
    if (half == 0) {
        sum += shsum[1][t];
        mx = fmaxf(mx, shmax[1][t]);
        float cntf = (float)(s1 - s0);
        float mean = sum / fmaxf(cntf, 1.0f);
        red[0][t] = mean * Wc[t * 3 + 0] + mx * Wc[(HF + t) * 3 + 0] + sum * Wc[(2 * HF + t) * 3 + 0];
        red[1][t] = mean * Wc[t * 3 + 1] + mx * Wc[(HF + t) * 3 + 1] + sum * Wc[(2 * HF + t) * 3 + 1];
        red[2][t] = mean * Wc[t * 3 + 2] + mx * Wc[(HF + t) * 3 + 2] + sum * Wc[(2 * HF + t) * 3 + 2];
    }
    __syncthreads();
    for (int o = 64; o > 0; o >>= 1) {
        if (half == 0 && t < o) {
            red[0][t] += red[0][t + o];
            red[1][t] += red[1][t + o];
            red[2][t] += red[2][t + o];
        }
        __syncthreads();
    }
    if (threadIdx.x < 3) out[g * 3 + threadIdx.x] = red[threadIdx.x][0] + bc[threadIdx.x];
}

extern "C" void kernel_launch(void* const* d_in, const int* in_sizes, int n_in,
                              void* d_out, int out_size, void* d_ws, size_t ws_size,
                              hipStream_t stream) {
    const float* x    = (const float*)d_in[0];
    const int*   ei   = (const int*)d_in[1];
    const int*   batch= (const int*)d_in[2];
    const float* W1   = (const float*)d_in[3];
    const float* b1   = (const float*)d_in[4];
    const float* g1   = (const float*)d_in[5];
    const float* be1  = (const float*)d_in[6];
    const float* W2   = (const float*)d_in[7];
    const float* b2   = (const float*)d_in[8];
    const float* g2   = (const float*)d_in[9];
    const float* be2  = (const float*)d_in[10];
    const float* Wc   = (const float*)d_in[11];
    const float* bc   = (const float*)d_in[12];
    float* out = (float*)d_out;

    const int N = in_sizes[0] / HF;
    const int E = in_sizes[1] / 2;
    const int NG = 256;
    const int* row = ei;
    const int* col = ei + E;
    const int total = N * HF;

    // workspace carve-up (256B aligned)
    char* w = (char*)d_ws;
    size_t off = 0;
    auto alloc = [&](size_t bytes) -> void* {
        void* p = w + off;
        off += (bytes + 255) & ~(size_t)255;
        return p;
    };
    int*            cnt_in   = (int*)alloc((size_t)N * 4);
    int*            fill     = (int*)alloc((size_t)N * 4);
    float*          dinv     = (float*)alloc((size_t)N * 4);
    int*            rowptr   = (int*)alloc(((size_t)N + 1) * 4);
    int*            blocksum = (int*)alloc(256 * 4);
    int*            gstart   = (int*)alloc((NG + 1) * 4);
    int2*           srs      = (int2*)alloc((size_t)E * 8);
    float*          ssum     = (float*)alloc(HF * 4);   // \ zeroed together
    float*          ssq      = (float*)alloc(HF * 4);   // /
    float*          scale    = (float*)alloc(HF * 4);
    float*          shift    = (float*)alloc(HF * 4);
    unsigned short* A        = (unsigned short*)alloc((size_t)total * 2);  // xw (bf16)
    float*          B        = (float*)alloc((size_t)total * 4);           // conv out (f32)

    const int T256 = 256;
    int gridE    = (E + T256 - 1) / T256;
    int gridN    = (N + T256 - 1) / T256;
    int gridGa   = (N + 7) / 8;
    int gridGemm = (N + 15) / 16;
    int nb       = (N + 255) / 256;  // scan blocks (requires N <= 65536)

    // --- CSR build (once; reused by both convs) ---
    hipMemsetAsync(cnt_in, 0, (size_t)N * 4, stream);
    deg_count<<<gridE, T256, 0, stream>>>(col, cnt_in, E);
    dinv_fin<<<gridN, T256, 0, stream>>>(cnt_in, dinv, N);
    scan_pass1<<<nb, 256, 0, stream>>>(cnt_in, rowptr, blocksum, N);
    scan_pass2<<<1, 256, 0, stream>>>(blocksum, nb, rowptr, N, E);
    scan_pass3<<<nb, 256, 0, stream>>>(rowptr, blocksum, fill, N);
    csr_fill<<<gridE, T256, 0, stream>>>(row, col, dinv, fill, srs, E);
    graph_bounds<<<2, 129, 0, stream>>>(batch, gstart, N, NG);

    // --- conv1 ---
    gemm128<<<gridGemm, 128, 0, stream>>>(x, W1, A, nullptr, nullptr, N, 0);
    gather_conv<<<gridGa, T256, 0, stream>>>(rowptr, srs, dinv, A, b1, B, N);
    hipMemsetAsync(ssum, 0, 2 * ((HF * 4 + 255) & ~255), stream);
    bn_stats<<<512, 128, 0, stream>>>(B, ssum, ssq, N);
    bn_finalize<<<1, 128, 0, stream>>>(ssum, ssq, g1, be1, scale, shift, N);

    // --- conv2 (BN1+ReLU fused into gemm input load) ---
    gemm128<<<gridGemm, 128, 0, stream>>>(B, W2, A, scale, shift, N, 1);
    gather_conv<<<gridGa, T256, 0, stream>>>(rowptr, srs, dinv, A, b2, B, N);
    hipMemsetAsync(ssum, 0, 2 * ((HF * 4 + 255) & ~255), stream);
    bn_stats<<<512, 128, 0, stream>>>(B, ssum, ssq, N);
    bn_finalize<<<1, 128, 0, stream>>>(ssum, ssq, g2, be2, scale, shift, N);

    // --- fused BN2+ReLU + pooling + classifier ---
    pool_classify<<<NG, 256, 0, stream>>>(B, gstart, scale, shift, Wc, bc, out);
}

// Round 4
// 483.995 us; speedup vs baseline: 12.0159x; 1.1067x over previous
//
#include <hip/hip_runtime.h>

#define HF 128  // feature width (F == H == 128)
#define NXCD 8

__device__ __forceinline__ float bf2f(unsigned short u) {
    return __uint_as_float(((unsigned)u) << 16);
}
__device__ __forceinline__ unsigned short f2bf(float f) {
    unsigned u = __float_as_uint(f);
    unsigned rounding = 0x7FFF + ((u >> 16) & 1);  // round-to-nearest-even
    return (unsigned short)((u + rounding) >> 16);
}

// ---------- degree histogram, XCD-partitioned by col-range ----------
// group g = blockIdx & 7 (maps to XCD g under round-robin dispatch) owns cols
// [g*step, g*step+step): its atomics stay in one XCD's L2 — no cross-XCD ping-pong.
__global__ __launch_bounds__(256) void deg_count_part(const int* __restrict__ col,
                                                      int* __restrict__ cnt,
                                                      int E, int step, int N) {
    int g = blockIdx.x & (NXCD - 1);
    int sub = blockIdx.x >> 3;
    int nsub = gridDim.x >> 3;
    int clo = g * step;
    int chi = min(clo + step, N);
    int stride = nsub * 256;
    for (int e = sub * 256 + threadIdx.x; e < E; e += stride) {
        int c = col[e];
        if (c >= clo && c < chi) atomicAdd(&cnt[c], 1);
    }
}

// ---------- scan pass1 + dinv fused ----------
__global__ __launch_bounds__(256) void scan_pass1(const int* __restrict__ cnt,
                                                  int* __restrict__ rowptr,
                                                  int* __restrict__ blocksum,
                                                  float* __restrict__ dinv, int N) {
    __shared__ int s[256];
    int t = threadIdx.x;
    int i = blockIdx.x * 256 + t;
    int v = (i < N) ? cnt[i] : 0;
    if (i < N) dinv[i] = rsqrtf((float)v + 1.0f);
    s[t] = v;
    __syncthreads();
    for (int o = 1; o < 256; o <<= 1) {
        int tv = (t >= o) ? s[t - o] : 0;
        __syncthreads();
        s[t] += tv;
        __syncthreads();
    }
    if (i < N) rowptr[i] = s[t] - v;  // block-local exclusive
    if (t == 255) blocksum[blockIdx.x] = s[255];
}

__global__ __launch_bounds__(256) void scan_pass2(int* __restrict__ blocksum, int nb,
                                                  int* __restrict__ rowptr, int N, int E) {
    __shared__ int s[256];
    int t = threadIdx.x;
    int v = (t < nb) ? blocksum[t] : 0;
    s[t] = v;
    __syncthreads();
    for (int o = 1; o < 256; o <<= 1) {
        int tv = (t >= o) ? s[t - o] : 0;
        __syncthreads();
        s[t] += tv;
        __syncthreads();
    }
    if (t < nb) blocksum[t] = s[t] - v;  // exclusive block bases
    if (t == 0) rowptr[N] = E;
}

// seeds fill[] with final rowptr so csr_fill can atomicAdd directly
__global__ __launch_bounds__(256) void scan_pass3(int* __restrict__ rowptr,
                                                  const int* __restrict__ blocksum,
                                                  int* __restrict__ fill, int N) {
    int i = blockIdx.x * 256 + threadIdx.x;
    if (i < N) {
        int v = rowptr[i] + blocksum[blockIdx.x];
        rowptr[i] = v;
        fill[i] = v;
    }
}

// ---------- CSR fill, XCD-partitioned by col-range ----------
// Bucket regions are monotone in col, so group g writes a contiguous ~E/8*8B
// region that fits its XCD's 4MB L2 -> sectors fill before writeback.
__global__ __launch_bounds__(256) void csr_fill_part(const int* __restrict__ row,
                                                     const int* __restrict__ col,
                                                     const float* __restrict__ dinv,
                                                     int* __restrict__ fill,
                                                     int2* __restrict__ srs,
                                                     int E, int step, int N) {
    int g = blockIdx.x & (NXCD - 1);
    int sub = blockIdx.x >> 3;
    int nsub = gridDim.x >> 3;
    int clo = g * step;
    int chi = min(clo + step, N);
    int stride = nsub * 256;
    for (int e = sub * 256 + threadIdx.x; e < E; e += stride) {
        int c = col[e];
        if (c >= clo && c < chi) {
            int r = row[e];
            int pos = atomicAdd(&fill[c], 1);
            srs[pos] = make_int2(r, __float_as_int(dinv[r]));
        }
    }
}

// ---------- GEMM: Y[N,128](bf16) = BNReLU?(X[N,128]) @ W[128,128] ----------
__global__ __launch_bounds__(128) void gemm128(const float* __restrict__ X,
                                               const float* __restrict__ W,
                                               unsigned short* __restrict__ Y,
                                               const float* __restrict__ scale,
                                               const float* __restrict__ shift,
                                               int N, int applyBN) {
    __shared__ float xs[16][HF];
    int t = threadIdx.x;
    int row0 = blockIdx.x * 16;
    float sc = applyBN ? scale[t] : 1.0f;
    float sh = applyBN ? shift[t] : 0.0f;
    for (int r = 0; r < 16; ++r) {
        int rr = row0 + r;
        float v = (rr < N) ? X[(size_t)rr * HF + t] : 0.0f;
        if (applyBN) v = fmaxf(v * sc + sh, 0.0f);
        xs[r][t] = v;
    }
    __syncthreads();
    for (int r0 = 0; r0 < 16; r0 += 4) {
        float a0 = 0.f, a1 = 0.f, a2 = 0.f, a3 = 0.f;
        #pragma unroll 8
        for (int f = 0; f < HF; ++f) {
            float w = W[f * HF + t];
            a0 += xs[r0 + 0][f] * w;
            a1 += xs[r0 + 1][f] * w;
            a2 += xs[r0 + 2][f] * w;
            a3 += xs[r0 + 3][f] * w;
        }
        int rr = row0 + r0;
        if (rr + 0 < N) Y[(size_t)(rr + 0) * HF + t] = f2bf(a0);
        if (rr + 1 < N) Y[(size_t)(rr + 1) * HF + t] = f2bf(a1);
        if (rr + 2 < N) Y[(size_t)(rr + 2) * HF + t] = f2bf(a2);
        if (rr + 3 < N) Y[(size_t)(rr + 3) * HF + t] = f2bf(a3);
    }
}

// ---------- gather-side conv: 16 lanes/node, uint4 (8 bf16) per lane ----------
// unpack trick: each u32 holds 2 bf16; hi half needs only a mask (no shift).
__global__ __launch_bounds__(256) void gather_conv(const int* __restrict__ rowptr,
                                                   const int2* __restrict__ srs,
                                                   const float* __restrict__ dinv,
                                                   const unsigned short* __restrict__ XW,
                                                   const float* __restrict__ b,
                                                   float* __restrict__ OUT, int N) {
    int c = blockIdx.x * 16 + (threadIdx.x >> 4);
    int j = threadIdx.x & 15;  // 8 features per lane
    if (c >= N) return;
    int e = rowptr[c], end = rowptr[c + 1];
    float acc[8] = {0.f, 0.f, 0.f, 0.f, 0.f, 0.f, 0.f, 0.f};
    const unsigned M = 0xffff0000u;
    for (; e + 1 < end; e += 2) {
        int2 p0 = srs[e], p1 = srs[e + 1];
        float d0 = __int_as_float(p0.y), d1 = __int_as_float(p1.y);
        uint4 u0 = *reinterpret_cast<const uint4*>(XW + (size_t)p0.x * HF + j * 8);
        uint4 u1 = *reinterpret_cast<const uint4*>(XW + (size_t)p1.x * HF + j * 8);
        acc[0] += d0 * __uint_as_float(u0.x << 16) + d1 * __uint_as_float(u1.x << 16);
        acc[1] += d0 * __uint_as_float(u0.x & M)   + d1 * __uint_as_float(u1.x & M);
        acc[2] += d0 * __uint_as_float(u0.y << 16) + d1 * __uint_as_float(u1.y << 16);
        acc[3] += d0 * __uint_as_float(u0.y & M)   + d1 * __uint_as_float(u1.y & M);
        acc[4] += d0 * __uint_as_float(u0.z << 16) + d1 * __uint_as_float(u1.z << 16);
        acc[5] += d0 * __uint_as_float(u0.z & M)   + d1 * __uint_as_float(u1.z & M);
        acc[6] += d0 * __uint_as_float(u0.w << 16) + d1 * __uint_as_float(u1.w << 16);
        acc[7] += d0 * __uint_as_float(u0.w & M)   + d1 * __uint_as_float(u1.w & M);
    }
    if (e < end) {
        int2 p0 = srs[e];
        float d0 = __int_as_float(p0.y);
        uint4 u0 = *reinterpret_cast<const uint4*>(XW + (size_t)p0.x * HF + j * 8);
        acc[0] += d0 * __uint_as_float(u0.x << 16);
        acc[1] += d0 * __uint_as_float(u0.x & M);
        acc[2] += d0 * __uint_as_float(u0.y << 16);
        acc[3] += d0 * __uint_as_float(u0.y & M);
        acc[4] += d0 * __uint_as_float(u0.z << 16);
        acc[5] += d0 * __uint_as_float(u0.z & M);
        acc[6] += d0 * __uint_as_float(u0.w << 16);
        acc[7] += d0 * __uint_as_float(u0.w & M);
    }
    float dc = dinv[c];
    uint4 xv = *reinterpret_cast<const uint4*>(XW + (size_t)c * HF + j * 8);
    float sx[8] = {
        __uint_as_float(xv.x << 16), __uint_as_float(xv.x & M),
        __uint_as_float(xv.y << 16), __uint_as_float(xv.y & M),
        __uint_as_float(xv.z << 16), __uint_as_float(xv.z & M),
        __uint_as_float(xv.w << 16), __uint_as_float(xv.w & M)};
    float4 b0 = *reinterpret_cast<const float4*>(b + j * 8);
    float4 b1 = *reinterpret_cast<const float4*>(b + j * 8 + 4);
    float4 o0, o1;
    o0.x = dc * (acc[0] + dc * sx[0]) + b0.x;
    o0.y = dc * (acc[1] + dc * sx[1]) + b0.y;
    o0.z = dc * (acc[2] + dc * sx[2]) + b0.z;
    o0.w = dc * (acc[3] + dc * sx[3]) + b0.w;
    o1.x = dc * (acc[4] + dc * sx[4]) + b1.x;
    o1.y = dc * (acc[5] + dc * sx[5]) + b1.y;
    o1.z = dc * (acc[6] + dc * sx[6]) + b1.z;
    o1.w = dc * (acc[7] + dc * sx[7]) + b1.w;
    float* op = OUT + (size_t)c * HF + j * 8;
    *reinterpret_cast<float4*>(op) = o0;
    *reinterpret_cast<float4*>(op + 4) = o1;
}

// ---------- BN stats ----------
__global__ __launch_bounds__(128) void bn_stats(const float* __restrict__ Y,
                                                float* __restrict__ ssum,
                                                float* __restrict__ ssq, int N) {
    int t = threadIdx.x;
    float s = 0.f, sq = 0.f;
    for (int n = blockIdx.x; n < N; n += gridDim.x) {
        float v = Y[(size_t)n * HF + t];
        s += v;
        sq += v * v;
    }
    atomicAdd(&ssum[t], s);
    atomicAdd(&ssq[t], sq);
}

__global__ __launch_bounds__(128) void bn_finalize(const float* __restrict__ ssum,
                                                   const float* __restrict__ ssq,
                                                   const float* __restrict__ gamma,
                                                   const float* __restrict__ beta,
                                                   float* __restrict__ scale,
                                                   float* __restrict__ shift, int N) {
    int t = threadIdx.x;
    float invn = 1.0f / (float)N;
    float mu = ssum[t] * invn;
    float var = ssq[t] * invn - mu * mu;
    float sc = gamma[t] * rsqrtf(var + 1e-5f);
    scale[t] = sc;
    shift[t] = beta[t] - mu * sc;
}

// ---------- graph boundaries (batch sorted) ----------
__global__ void graph_bounds(const int* __restrict__ batch, int* __restrict__ gstart,
                             int N, int NG) {
    int g = blockIdx.x * blockDim.x + threadIdx.x;
    if (g > NG) return;
    int lo = 0, hi = N;
    while (lo < hi) {
        int mid = (lo + hi) >> 1;
        if (batch[mid] < g) lo = mid + 1; else hi = mid;
    }
    gstart[g] = lo;
}

// ---------- fused BN2+ReLU + mean/max/sum pool + classifier ----------
__global__ __launch_bounds__(256) void pool_classify(const float* __restrict__ B,
                                                     const int* __restrict__ gstart,
                                                     const float* __restrict__ scale,
                                                     const float* __restrict__ shift,
                                                     const float* __restrict__ Wc,
                                                     const float* __restrict__ bc,
                                                     float* __restrict__ out) {
    int g = blockIdx.x;
    int t = threadIdx.x & 127;
    int half = threadIdx.x >> 7;
    int s0 = gstart[g], s1 = gstart[g + 1];
    float sc = scale[t], sh = shift[t];
    float sum = 0.f, mx = 0.f;  // 0-init == empty-graph guard (post-ReLU v >= 0)
    for (int n = s0 + half; n < s1; n += 2) {
        float v = fmaxf(B[(size_t)n * HF + t] * sc + sh, 0.0f);
        sum += v;
        mx = fmaxf(mx, v);
    }
    __shared__ float shsum[2][HF], shmax[2][HF];
    __shared__ float red[3][HF];
    shsum[half][t] = sum;
    shmax[half][t] = mx;
    __syncthreads();
    if (half == 0) {
        sum += shsum[1][t];
        mx = fmaxf(mx, shmax[1][t]);
        float cntf = (float)(s1 - s0);
        float mean = sum / fmaxf(cntf, 1.0f);
        red[0][t] = mean * Wc[t * 3 + 0] + mx * Wc[(HF + t) * 3 + 0] + sum * Wc[(2 * HF + t) * 3 + 0];
        red[1][t] = mean * Wc[t * 3 + 1] + mx * Wc[(HF + t) * 3 + 1] + sum * Wc[(2 * HF + t) * 3 + 1];
        red[2][t] = mean * Wc[t * 3 + 2] + mx * Wc[(HF + t) * 3 + 2] + sum * Wc[(2 * HF + t) * 3 + 2];
    }
    __syncthreads();
    for (int o = 64; o > 0; o >>= 1) {
        if (half == 0 && t < o) {
            red[0][t] += red[0][t + o];
            red[1][t] += red[1][t + o];
            red[2][t] += red[2][t + o];
        }
        __syncthreads();
    }
    if (threadIdx.x < 3) out[g * 3 + threadIdx.x] = red[threadIdx.x][0] + bc[threadIdx.x];
}

extern "C" void kernel_launch(void* const* d_in, const int* in_sizes, int n_in,
                              void* d_out, int out_size, void* d_ws, size_t ws_size,
                              hipStream_t stream) {
    const float* x    = (const float*)d_in[0];
    const int*   ei   = (const int*)d_in[1];
    const int*   batch= (const int*)d_in[2];
    const float* W1   = (const float*)d_in[3];
    const float* b1   = (const float*)d_in[4];
    const float* g1   = (const float*)d_in[5];
    const float* be1  = (const float*)d_in[6];
    const float* W2   = (const float*)d_in[7];
    const float* b2   = (const float*)d_in[8];
    const float* g2   = (const float*)d_in[9];
    const float* be2  = (const float*)d_in[10];
    const float* Wc   = (const float*)d_in[11];
    const float* bc   = (const float*)d_in[12];
    float* out = (float*)d_out;

    const int N = in_sizes[0] / HF;
    const int E = in_sizes[1] / 2;
    const int NG = 256;
    const int* row = ei;
    const int* col = ei + E;
    const int total = N * HF;
    const int step = (N + NXCD - 1) / NXCD;

    // workspace carve-up (256B aligned)
    char* w = (char*)d_ws;
    size_t off = 0;
    auto alloc = [&](size_t bytes) -> void* {
        void* p = w + off;
        off += (bytes + 255) & ~(size_t)255;
        return p;
    };
    int*            cnt_in   = (int*)alloc((size_t)N * 4);
    int*            fill     = (int*)alloc((size_t)N * 4);
    float*          dinv     = (float*)alloc((size_t)N * 4);
    int*            rowptr   = (int*)alloc(((size_t)N + 1) * 4);
    int*            blocksum = (int*)alloc(256 * 4);
    int*            gstart   = (int*)alloc((NG + 1) * 4);
    int2*           srs      = (int2*)alloc((size_t)E * 8);
    float*          ssum     = (float*)alloc(HF * 4);   // \ zeroed together
    float*          ssq      = (float*)alloc(HF * 4);   // /
    float*          scale    = (float*)alloc(HF * 4);
    float*          shift    = (float*)alloc(HF * 4);
    unsigned short* A        = (unsigned short*)alloc((size_t)total * 2);  // xw (bf16)
    float*          B        = (float*)alloc((size_t)total * 4);           // conv out (f32)

    const int T256 = 256;
    int gridGa   = (N + 15) / 16;
    int gridGemm = (N + 15) / 16;
    int nb       = (N + 255) / 256;   // scan blocks (requires N <= 65536)
    int gridPart = NXCD * 192;        // 8 XCD groups x 192 sub-blocks

    // --- CSR build (once; reused by both convs) ---
    hipMemsetAsync(cnt_in, 0, (size_t)N * 4, stream);
    deg_count_part<<<gridPart, T256, 0, stream>>>(col, cnt_in, E, step, N);
    scan_pass1<<<nb, 256, 0, stream>>>(cnt_in, rowptr, blocksum, dinv, N);
    scan_pass2<<<1, 256, 0, stream>>>(blocksum, nb, rowptr, N, E);
    scan_pass3<<<nb, 256, 0, stream>>>(rowptr, blocksum, fill, N);
    csr_fill_part<<<gridPart, T256, 0, stream>>>(row, col, dinv, fill, srs, E, step, N);
    graph_bounds<<<2, 129, 0, stream>>>(batch, gstart, N, NG);

    // --- conv1 ---
    gemm128<<<gridGemm, 128, 0, stream>>>(x, W1, A, nullptr, nullptr, N, 0);
    gather_conv<<<gridGa, T256, 0, stream>>>(rowptr, srs, dinv, A, b1, B, N);
    hipMemsetAsync(ssum, 0, 2 * ((HF * 4 + 255) & ~255), stream);
    bn_stats<<<512, 128, 0, stream>>>(B, ssum, ssq, N);
    bn_finalize<<<1, 128, 0, stream>>>(ssum, ssq, g1, be1, scale, shift, N);

    // --- conv2 (BN1+ReLU fused into gemm input load) ---
    gemm128<<<gridGemm, 128, 0, stream>>>(B, W2, A, scale, shift, N, 1);
    gather_conv<<<gridGa, T256, 0, stream>>>(rowptr, srs, dinv, A, b2, B, N);
    hipMemsetAsync(ssum, 0, 2 * ((HF * 4 + 255) & ~255), stream);
    bn_stats<<<512, 128, 0, stream>>>(B, ssum, ssq, N);
    bn_finalize<<<1, 128, 0, stream>>>(ssum, ssq, g2, be2, scale, shift, N);

    // --- fused BN2+ReLU + pooling + classifier ---
    pool_classify<<<NG, 256, 0, stream>>>(B, gstart, scale, shift, Wc, bc, out);
}

// Round 5
// 481.688 us; speedup vs baseline: 12.0735x; 1.0048x over previous
//
#include <hip/hip_runtime.h>

#define HF 128  // feature width (F == H == 128)
#define NXCD 8

__device__ __forceinline__ unsigned short f2bf(float f) {
    unsigned u = __float_as_uint(f);
    unsigned rounding = 0x7FFF + ((u >> 16) & 1);  // round-to-nearest-even
    return (unsigned short)((u + rounding) >> 16);
}

// ---------- degree histogram, XCD-partitioned by col-range ----------
// group g = blockIdx & 7 (maps to XCD g under round-robin dispatch) owns cols
// [g*step, g*step+step): its atomics stay in one XCD's L2 — no cross-XCD ping-pong.
// col stream is non-temporal so it doesn't thrash the cnt lines out of L2.
__global__ __launch_bounds__(256) void deg_count_part(const int* __restrict__ col,
                                                      int* __restrict__ cnt,
                                                      int E, int step, int N) {
    int g = blockIdx.x & (NXCD - 1);
    int sub = blockIdx.x >> 3;
    int nsub = gridDim.x >> 3;
    int clo = g * step;
    int chi = min(clo + step, N);
    int stride = nsub * 256;
    for (int e = sub * 256 + threadIdx.x; e < E; e += stride) {
        int c = __builtin_nontemporal_load(&col[e]);
        if (c >= clo && c < chi) atomicAdd(&cnt[c], 1);
    }
}

// ---------- scan pass1 + dinv fused ----------
__global__ __launch_bounds__(256) void scan_pass1(const int* __restrict__ cnt,
                                                  int* __restrict__ rowptr,
                                                  int* __restrict__ blocksum,
                                                  float* __restrict__ dinv, int N) {
    __shared__ int s[256];
    int t = threadIdx.x;
    int i = blockIdx.x * 256 + t;
    int v = (i < N) ? cnt[i] : 0;
    if (i < N) dinv[i] = rsqrtf((float)v + 1.0f);
    s[t] = v;
    __syncthreads();
    for (int o = 1; o < 256; o <<= 1) {
        int tv = (t >= o) ? s[t - o] : 0;
        __syncthreads();
        s[t] += tv;
        __syncthreads();
    }
    if (i < N) rowptr[i] = s[t] - v;  // block-local exclusive
    if (t == 255) blocksum[blockIdx.x] = s[255];
}

__global__ __launch_bounds__(256) void scan_pass2(int* __restrict__ blocksum, int nb,
                                                  int* __restrict__ rowptr, int N, int E) {
    __shared__ int s[256];
    int t = threadIdx.x;
    int v = (t < nb) ? blocksum[t] : 0;
    s[t] = v;
    __syncthreads();
    for (int o = 1; o < 256; o <<= 1) {
        int tv = (t >= o) ? s[t - o] : 0;
        __syncthreads();
        s[t] += tv;
        __syncthreads();
    }
    if (t < nb) blocksum[t] = s[t] - v;  // exclusive block bases
    if (t == 0) rowptr[N] = E;
}

// seeds fill[] with final rowptr so csr_fill can atomicAdd directly
__global__ __launch_bounds__(256) void scan_pass3(int* __restrict__ rowptr,
                                                  const int* __restrict__ blocksum,
                                                  int* __restrict__ fill, int N) {
    int i = blockIdx.x * 256 + threadIdx.x;
    if (i < N) {
        int v = rowptr[i] + blocksum[blockIdx.x];
        rowptr[i] = v;
        fill[i] = v;
    }
}

// ---------- CSR fill, XCD-partitioned by col-range; payload = bare row index ----------
__global__ __launch_bounds__(256) void csr_fill_part(const int* __restrict__ row,
                                                     const int* __restrict__ col,
                                                     int* __restrict__ fill,
                                                     int* __restrict__ srow,
                                                     int E, int step, int N) {
    int g = blockIdx.x & (NXCD - 1);
    int sub = blockIdx.x >> 3;
    int nsub = gridDim.x >> 3;
    int clo = g * step;
    int chi = min(clo + step, N);
    int stride = nsub * 256;
    for (int e = sub * 256 + threadIdx.x; e < E; e += stride) {
        int c = __builtin_nontemporal_load(&col[e]);
        if (c >= clo && c < chi) {
            int r = __builtin_nontemporal_load(&row[e]);
            int pos = atomicAdd(&fill[c], 1);
            srow[pos] = r;
        }
    }
}

// ---------- GEMM: Y[N,128](bf16) = rowscale[r] * (BNReLU?(X[N,128]) @ W[128,128]) ----------
__global__ __launch_bounds__(128) void gemm128(const float* __restrict__ X,
                                               const float* __restrict__ W,
                                               unsigned short* __restrict__ Y,
                                               const float* __restrict__ scale,
                                               const float* __restrict__ shift,
                                               const float* __restrict__ rowscale,
                                               int N, int applyBN) {
    __shared__ float xs[16][HF];
    int t = threadIdx.x;
    int row0 = blockIdx.x * 16;
    float sc = applyBN ? scale[t] : 1.0f;
    float sh = applyBN ? shift[t] : 0.0f;
    for (int r = 0; r < 16; ++r) {
        int rr = row0 + r;
        float v = (rr < N) ? X[(size_t)rr * HF + t] : 0.0f;
        if (applyBN) v = fmaxf(v * sc + sh, 0.0f);
        xs[r][t] = v;
    }
    __syncthreads();
    for (int r0 = 0; r0 < 16; r0 += 4) {
        float a0 = 0.f, a1 = 0.f, a2 = 0.f, a3 = 0.f;
        #pragma unroll 8
        for (int f = 0; f < HF; ++f) {
            float w = W[f * HF + t];
            a0 += xs[r0 + 0][f] * w;
            a1 += xs[r0 + 1][f] * w;
            a2 += xs[r0 + 2][f] * w;
            a3 += xs[r0 + 3][f] * w;
        }
        int rr = row0 + r0;
        if (rr + 0 < N) Y[(size_t)(rr + 0) * HF + t] = f2bf(a0 * rowscale[rr + 0]);
        if (rr + 1 < N) Y[(size_t)(rr + 1) * HF + t] = f2bf(a1 * rowscale[rr + 1]);
        if (rr + 2 < N) Y[(size_t)(rr + 2) * HF + t] = f2bf(a2 * rowscale[rr + 2]);
        if (rr + 3 < N) Y[(size_t)(rr + 3) * HF + t] = f2bf(a3 * rowscale[rr + 3]);
    }
}

// ---------- gather-side conv on pre-scaled bf16 XWs: OUT[c] = dc*(sum_e XWs[srow[e]] + XWs[c]) + b ----------
// 16 lanes/node, uint4 (8 bf16) per lane; hi-half unpack is a mask (no shift).
__global__ __launch_bounds__(256) void gather_conv(const int* __restrict__ rowptr,
                                                   const int* __restrict__ srow,
                                                   const float* __restrict__ dinv,
                                                   const unsigned short* __restrict__ XW,
                                                   const float* __restrict__ b,
                                                   float* __restrict__ OUT, int N) {
    int c = blockIdx.x * 16 + (threadIdx.x >> 4);
    int j = threadIdx.x & 15;  // 8 features per lane
    if (c >= N) return;
    int e = rowptr[c], end = rowptr[c + 1];
    float acc[8] = {0.f, 0.f, 0.f, 0.f, 0.f, 0.f, 0.f, 0.f};
    const unsigned M = 0xffff0000u;
    for (; e + 1 < end; e += 2) {
        int r0 = srow[e], r1 = srow[e + 1];
        uint4 u0 = *reinterpret_cast<const uint4*>(XW + (size_t)r0 * HF + j * 8);
        uint4 u1 = *reinterpret_cast<const uint4*>(XW + (size_t)r1 * HF + j * 8);
        acc[0] += __uint_as_float(u0.x << 16) + __uint_as_float(u1.x << 16);
        acc[1] += __uint_as_float(u0.x & M)   + __uint_as_float(u1.x & M);
        acc[2] += __uint_as_float(u0.y << 16) + __uint_as_float(u1.y << 16);
        acc[3] += __uint_as_float(u0.y & M)   + __uint_as_float(u1.y & M);
        acc[4] += __uint_as_float(u0.z << 16) + __uint_as_float(u1.z << 16);
        acc[5] += __uint_as_float(u0.z & M)   + __uint_as_float(u1.z & M);
        acc[6] += __uint_as_float(u0.w << 16) + __uint_as_float(u1.w << 16);
        acc[7] += __uint_as_float(u0.w & M)   + __uint_as_float(u1.w & M);
    }
    if (e < end) {
        int r0 = srow[e];
        uint4 u0 = *reinterpret_cast<const uint4*>(XW + (size_t)r0 * HF + j * 8);
        acc[0] += __uint_as_float(u0.x << 16);
        acc[1] += __uint_as_float(u0.x & M);
        acc[2] += __uint_as_float(u0.y << 16);
        acc[3] += __uint_as_float(u0.y & M);
        acc[4] += __uint_as_float(u0.z << 16);
        acc[5] += __uint_as_float(u0.z & M);
        acc[6] += __uint_as_float(u0.w << 16);
        acc[7] += __uint_as_float(u0.w & M);
    }
    float dc = dinv[c];
    uint4 xv = *reinterpret_cast<const uint4*>(XW + (size_t)c * HF + j * 8);
    acc[0] += __uint_as_float(xv.x << 16);
    acc[1] += __uint_as_float(xv.x & M);
    acc[2] += __uint_as_float(xv.y << 16);
    acc[3] += __uint_as_float(xv.y & M);
    acc[4] += __uint_as_float(xv.z << 16);
    acc[5] += __uint_as_float(xv.z & M);
    acc[6] += __uint_as_float(xv.w << 16);
    acc[7] += __uint_as_float(xv.w & M);
    float4 b0 = *reinterpret_cast<const float4*>(b + j * 8);
    float4 b1 = *reinterpret_cast<const float4*>(b + j * 8 + 4);
    float4 o0, o1;
    o0.x = dc * acc[0] + b0.x;
    o0.y = dc * acc[1] + b0.y;
    o0.z = dc * acc[2] + b0.z;
    o0.w = dc * acc[3] + b0.w;
    o1.x = dc * acc[4] + b1.x;
    o1.y = dc * acc[5] + b1.y;
    o1.z = dc * acc[6] + b1.z;
    o1.w = dc * acc[7] + b1.w;
    float* op = OUT + (size_t)c * HF + j * 8;
    *reinterpret_cast<float4*>(op) = o0;
    *reinterpret_cast<float4*>(op + 4) = o1;
}

// ---------- BN stats ----------
__global__ __launch_bounds__(128) void bn_stats(const float* __restrict__ Y,
                                                float* __restrict__ ssum,
                                                float* __restrict__ ssq, int N) {
    int t = threadIdx.x;
    float s = 0.f, sq = 0.f;
    for (int n = blockIdx.x; n < N; n += gridDim.x) {
        float v = Y[(size_t)n * HF + t];
        s += v;
        sq += v * v;
    }
    atomicAdd(&ssum[t], s);
    atomicAdd(&ssq[t], sq);
}

__global__ __launch_bounds__(128) void bn_finalize(const float* __restrict__ ssum,
                                                   const float* __restrict__ ssq,
                                                   const float* __restrict__ gamma,
                                                   const float* __restrict__ beta,
                                                   float* __restrict__ scale,
                                                   float* __restrict__ shift, int N) {
    int t = threadIdx.x;
    float invn = 1.0f / (float)N;
    float mu = ssum[t] * invn;
    float var = ssq[t] * invn - mu * mu;
    float sc = gamma[t] * rsqrtf(var + 1e-5f);
    scale[t] = sc;
    shift[t] = beta[t] - mu * sc;
}

// ---------- graph boundaries (batch sorted) ----------
__global__ void graph_bounds(const int* __restrict__ batch, int* __restrict__ gstart,
                             int N, int NG) {
    int g = blockIdx.x * blockDim.x + threadIdx.x;
    if (g > NG) return;
    int lo = 0, hi = N;
    while (lo < hi) {
        int mid = (lo + hi) >> 1;
        if (batch[mid] < g) lo = mid + 1; else hi = mid;
    }
    gstart[g] = lo;
}

// ---------- fused BN2+ReLU + mean/max/sum pool + classifier ----------
__global__ __launch_bounds__(256) void pool_classify(const float* __restrict__ B,
                                                     const int* __restrict__ gstart,
                                                     const float* __restrict__ scale,
                                                     const float* __restrict__ shift,
                                                     const float* __restrict__ Wc,
                                                     const float* __restrict__ bc,
                                                     float* __restrict__ out) {
    int g = blockIdx.x;
    int t = threadIdx.x & 127;
    int half = threadIdx.x >> 7;
    int s0 = gstart[g], s1 = gstart[g + 1];
    float sc = scale[t], sh = shift[t];
    float sum = 0.f, mx = 0.f;  // 0-init == empty-graph guard (post-ReLU v >= 0)
    for (int n = s0 + half; n < s1; n += 2) {
        float v = fmaxf(B[(size_t)n * HF + t] * sc + sh, 0.0f);
        sum += v;
        mx = fmaxf(mx, v);
    }
    __shared__ float shsum[2][HF], shmax[2][HF];
    __shared__ float red[3][HF];
    shsum[half][t] = sum;
    shmax[half][t] = mx;
    __syncthreads();
    if (half == 0) {
        sum += shsum[1][t];
        mx = fmaxf(mx, shmax[1][t]);
        float cntf = (float)(s1 - s0);
        float mean = sum / fmaxf(cntf, 1.0f);
        red[0][t] = mean * Wc[t * 3 + 0] + mx * Wc[(HF + t) * 3 + 0] + sum * Wc[(2 * HF + t) * 3 + 0];
        red[1][t] = mean * Wc[t * 3 + 1] + mx * Wc[(HF + t) * 3 + 1] + sum * Wc[(2 * HF + t) * 3 + 1];
        red[2][t] = mean * Wc[t * 3 + 2] + mx * Wc[(HF + t) * 3 + 2] + sum * Wc[(2 * HF + t) * 3 + 2];
    }
    __syncthreads();
    for (int o = 64; o > 0; o >>= 1) {
        if (half == 0 && t < o) {
            red[0][t] += red[0][t + o];
            red[1][t] += red[1][t + o];
            red[2][t] += red[2][t + o];
        }
        __syncthreads();
    }
    if (threadIdx.x < 3) out[g * 3 + threadIdx.x] = red[threadIdx.x][0] + bc[threadIdx.x];
}

extern "C" void kernel_launch(void* const* d_in, const int* in_sizes, int n_in,
                              void* d_out, int out_size, void* d_ws, size_t ws_size,
                              hipStream_t stream) {
    const float* x    = (const float*)d_in[0];
    const int*   ei   = (const int*)d_in[1];
    const int*   batch= (const int*)d_in[2];
    const float* W1   = (const float*)d_in[3];
    const float* b1   = (const float*)d_in[4];
    const float* g1   = (const float*)d_in[5];
    const float* be1  = (const float*)d_in[6];
    const float* W2   = (const float*)d_in[7];
    const float* b2   = (const float*)d_in[8];
    const float* g2   = (const float*)d_in[9];
    const float* be2  = (const float*)d_in[10];
    const float* Wc   = (const float*)d_in[11];
    const float* bc   = (const float*)d_in[12];
    float* out = (float*)d_out;

    const int N = in_sizes[0] / HF;
    const int E = in_sizes[1] / 2;
    const int NG = 256;
    const int* row = ei;
    const int* col = ei + E;
    const int total = N * HF;
    const int step = (N + NXCD - 1) / NXCD;

    // workspace carve-up (256B aligned)
    char* w = (char*)d_ws;
    size_t off = 0;
    auto alloc = [&](size_t bytes) -> void* {
        void* p = w + off;
        off += (bytes + 255) & ~(size_t)255;
        return p;
    };
    int*            cnt_in   = (int*)alloc((size_t)N * 4);
    int*            fill     = (int*)alloc((size_t)N * 4);
    float*          dinv     = (float*)alloc((size_t)N * 4);
    int*            rowptr   = (int*)alloc(((size_t)N + 1) * 4);
    int*            blocksum = (int*)alloc(256 * 4);
    int*            gstart   = (int*)alloc((NG + 1) * 4);
    int*            srow     = (int*)alloc((size_t)E * 4);
    float*          ssum     = (float*)alloc(HF * 4);   // \ zeroed together
    float*          ssq      = (float*)alloc(HF * 4);   // /
    float*          scale    = (float*)alloc(HF * 4);
    float*          shift    = (float*)alloc(HF * 4);
    unsigned short* A        = (unsigned short*)alloc((size_t)total * 2);  // dinv-scaled xw (bf16)
    float*          B        = (float*)alloc((size_t)total * 4);           // conv out (f32)

    const int T256 = 256;
    int gridGa   = (N + 15) / 16;
    int gridGemm = (N + 15) / 16;
    int nb       = (N + 255) / 256;   // scan blocks (requires N <= 65536)
    int gridPart = NXCD * 192;        // 8 XCD groups x 192 sub-blocks

    // --- CSR build (once; reused by both convs) ---
    hipMemsetAsync(cnt_in, 0, (size_t)N * 4, stream);
    deg_count_part<<<gridPart, T256, 0, stream>>>(col, cnt_in, E, step, N);
    scan_pass1<<<nb, 256, 0, stream>>>(cnt_in, rowptr, blocksum, dinv, N);
    scan_pass2<<<1, 256, 0, stream>>>(blocksum, nb, rowptr, N, E);
    scan_pass3<<<nb, 256, 0, stream>>>(rowptr, blocksum, fill, N);
    csr_fill_part<<<gridPart, T256, 0, stream>>>(row, col, fill, srow, E, step, N);
    graph_bounds<<<2, 129, 0, stream>>>(batch, gstart, N, NG);

    // --- conv1 (GEMM output rows pre-scaled by dinv) ---
    gemm128<<<gridGemm, 128, 0, stream>>>(x, W1, A, nullptr, nullptr, dinv, N, 0);
    gather_conv<<<gridGa, T256, 0, stream>>>(rowptr, srow, dinv, A, b1, B, N);
    hipMemsetAsync(ssum, 0, 2 * ((HF * 4 + 255) & ~255), stream);
    bn_stats<<<512, 128, 0, stream>>>(B, ssum, ssq, N);
    bn_finalize<<<1, 128, 0, stream>>>(ssum, ssq, g1, be1, scale, shift, N);

    // --- conv2 (BN1+ReLU fused into gemm input load) ---
    gemm128<<<gridGemm, 128, 0, stream>>>(B, W2, A, scale, shift, dinv, N, 1);
    gather_conv<<<gridGa, T256, 0, stream>>>(rowptr, srow, dinv, A, b2, B, N);
    hipMemsetAsync(ssum, 0, 2 * ((HF * 4 + 255) & ~255), stream);
    bn_stats<<<512, 128, 0, stream>>>(B, ssum, ssq, N);
    bn_finalize<<<1, 128, 0, stream>>>(ssum, ssq, g2, be2, scale, shift, N);

    // --- fused BN2+ReLU + pooling + classifier ---
    pool_classify<<<NG, 256, 0, stream>>>(B, gstart, scale, shift, Wc, bc, out);
}